// Round 9
// baseline (280.214 us; speedup 1.0000x reference)
//
#include <hip/hip_runtime.h>

// GCN: 2x GCNConv(sym-norm, self-loops) + mean-pool + linear head.
// Round 9: layer-2 agg back to one-node-per-wave (TLP is king for the
// L2-latency-bound gather; round-8's grid-stride fusion cost 10x waves),
// pooling via non-atomic per-block partials + small reduce kernel.
// Pair-gather (2 edges/wave-load) kept, inner loop deepened to 16 edges.

#define FEAT 128
#define TILE 4096    // edges per bucketing workgroup (k_p1/k_p3)
#define VPT  40      // bscan elems per thread (covers B*NW = 196*196)

typedef __attribute__((ext_vector_type(8))) short short8;    // 8 bf16
typedef __attribute__((ext_vector_type(4))) float float4v;   // 4 fp32 acc
typedef __attribute__((ext_vector_type(2))) float floatx2;

__device__ __forceinline__ unsigned int f2b(float f) {       // rne bf16 (as uint)
    unsigned int u = __float_as_uint(f);
    return (u + 0x7fffu + ((u >> 16) & 1u)) >> 16;
}

// decode 4 fp8 (one uint) and accumulate
__device__ __forceinline__ void dec4(unsigned int q, float* a) {
    floatx2 lo = __builtin_amdgcn_cvt_pk_f32_fp8(q, false);
    floatx2 hi = __builtin_amdgcn_cvt_pk_f32_fp8(q, true);
    a[0] += lo[0]; a[1] += lo[1]; a[2] += hi[0]; a[3] += hi[1];
}

// ---- pair-gather: node n's neighbor-sum over fp8 rows (32 uints each). ----
// half = lane>>5 picks the edge within a pair; lp = lane&31 picks 4 feats.
// After the shfl merge BOTH halves hold the full sum of feats {4lp..4lp+3}.
__device__ __forceinline__ void gather_node(const unsigned int* __restrict__ Xq32,
                                            const unsigned short* __restrict__ csr,
                                            int beg, int end, int n,
                                            int half, int lp, float* a) {
    a[0] = a[1] = a[2] = a[3] = 0.f;
    if (half == 0) dec4(Xq32[(size_t)n * 32 + lp], a);        // self term
    int e = beg;
    if ((e & 1) && e < end) {                                 // align to even
        if (half == 0) dec4(Xq32[(size_t)csr[e] * 32 + lp], a);
        ++e;
    }
    const unsigned int* c32 = (const unsigned int*)csr;
    int sh = half * 16;
    for (; e + 16 <= end; e += 16) {                          // 16 edges in flight
        int w = e >> 1;
        unsigned int w0 = c32[w],     w1 = c32[w + 1], w2 = c32[w + 2], w3 = c32[w + 3];
        unsigned int w4 = c32[w + 4], w5 = c32[w + 5], w6 = c32[w + 6], w7 = c32[w + 7];
        int s0 = (w0 >> sh) & 0xffff, s1 = (w1 >> sh) & 0xffff;
        int s2 = (w2 >> sh) & 0xffff, s3 = (w3 >> sh) & 0xffff;
        int s4 = (w4 >> sh) & 0xffff, s5 = (w5 >> sh) & 0xffff;
        int s6 = (w6 >> sh) & 0xffff, s7 = (w7 >> sh) & 0xffff;
        unsigned int q0 = Xq32[(size_t)s0 * 32 + lp];
        unsigned int q1 = Xq32[(size_t)s1 * 32 + lp];
        unsigned int q2 = Xq32[(size_t)s2 * 32 + lp];
        unsigned int q3 = Xq32[(size_t)s3 * 32 + lp];
        unsigned int q4 = Xq32[(size_t)s4 * 32 + lp];
        unsigned int q5 = Xq32[(size_t)s5 * 32 + lp];
        unsigned int q6 = Xq32[(size_t)s6 * 32 + lp];
        unsigned int q7 = Xq32[(size_t)s7 * 32 + lp];
        dec4(q0, a); dec4(q1, a); dec4(q2, a); dec4(q3, a);
        dec4(q4, a); dec4(q5, a); dec4(q6, a); dec4(q7, a);
    }
    for (; e + 2 <= end; e += 2)
        dec4(Xq32[(size_t)csr[e + half] * 32 + lp], a);
    if (e < end && half == 0)
        dec4(Xq32[(size_t)csr[e] * 32 + lp], a);
#pragma unroll
    for (int j = 0; j < 4; ++j) a[j] += __shfl_xor(a[j], 32);
}

// ---------------- bucketed CSR build (bucket = dst>>8, 256 nodes) -----------

__global__ __launch_bounds__(1024) void k_p1(const int* __restrict__ dst,
                                             int* __restrict__ cnt, int E, int B, int NW) {
    __shared__ int h[256];
    int t = threadIdx.x, w = blockIdx.x;
    if (t < 256) h[t] = 0;
    __syncthreads();
    int e0 = w * TILE, e1 = min(e0 + TILE, E);
    for (int e = e0 + t; e < e1; e += 1024) atomicAdd(&h[dst[e] >> 8], 1);
    __syncthreads();
    if (t < B) cnt[t * NW + w] = h[t];      // bucket-major
}

__global__ __launch_bounds__(1024) void k_bscan(int* __restrict__ cnt, int L) {
    __shared__ int s[1024];
    int t = threadIdx.x;
    int v[VPT]; int sum = 0;
#pragma unroll
    for (int j = 0; j < VPT; ++j) {
        int idx = t * VPT + j;
        int x = (idx < L) ? cnt[idx] : 0;
        v[j] = sum; sum += x;
    }
    s[t] = sum;
    __syncthreads();
    for (int d = 1; d < 1024; d <<= 1) {
        int x = (t >= d) ? s[t - d] : 0;
        __syncthreads();
        s[t] += x;
        __syncthreads();
    }
    int pre = (t > 0) ? s[t - 1] : 0;
#pragma unroll
    for (int j = 0; j < VPT; ++j) {
        int idx = t * VPT + j;
        if (idx < L) cnt[idx] = pre + v[j];
    }
}

__global__ __launch_bounds__(1024) void k_p3(const int* __restrict__ src,
                                             const int* __restrict__ dst,
                                             const int* __restrict__ cnt,
                                             unsigned int* __restrict__ ebuf,
                                             int E, int B, int NW) {
    __shared__ int cur[256];
    int t = threadIdx.x, w = blockIdx.x;
    if (t < B) cur[t] = cnt[t * NW + w];
    __syncthreads();
    int e0 = w * TILE, e1 = min(e0 + TILE, E);
    for (int e = e0 + t; e < e1; e += 1024) {
        int d = dst[e], s = src[e];
        int p = atomicAdd(&cur[d >> 8], 1);
        ebuf[p] = ((unsigned int)d << 16) | (unsigned int)s;
    }
}

// per bucket: histogram -> isd, intra-bucket scan -> off, scatter -> csr
__global__ __launch_bounds__(256) void k_p4(const unsigned int* __restrict__ ebuf,
                                            const int* __restrict__ cnt,
                                            float* __restrict__ isd,
                                            int* __restrict__ off,
                                            unsigned short* __restrict__ csr,
                                            int E, int B, int NW, int N) {
    __shared__ int h[256], s[256], cur[256];
    int t = threadIdx.x, b = blockIdx.x;
    h[t] = 0;
    __syncthreads();
    int s0 = cnt[b * NW];
    int s1e = (b + 1 < B) ? cnt[(b + 1) * NW] : E;
    for (int e = s0 + t; e < s1e; e += 256)
        atomicAdd(&h[(ebuf[e] >> 16) & 255], 1);
    __syncthreads();
    int own = h[t];
    s[t] = own;
    __syncthreads();
    for (int d = 1; d < 256; d <<= 1) {
        int x = (t >= d) ? s[t - d] : 0;
        __syncthreads();
        s[t] += x;
        __syncthreads();
    }
    int node = (b << 8) + t;
    int myoff = s0 + s[t] - own;
    cur[t] = myoff;
    if (node < N) {
        isd[node] = rsqrtf((float)(own + 1));        // +1 self-loop
        off[node] = myoff;
        if (node == N - 1) off[N] = s0 + s[t];       // == E
    }
    __syncthreads();
    for (int e = s0 + t; e < s1e; e += 256) {
        unsigned int v = ebuf[e];
        int p = atomicAdd(&cur[(v >> 16) & 255], 1);
        csr[p] = (unsigned short)(v & 0xffffu);
    }
}

// ---------------- prep: x->fp8 scaled, weight swizzles, pool zero -----------

__device__ __forceinline__ void wswz_one(const float* W, unsigned short* out,
                                         int N, int tid) {
    int lane = tid & 63, f = tid >> 6;
    int NT = N >> 4;
    int nt = f % NT, kt = f / NT;
    int m = lane & 15, quad = lane >> 4;
    short8 pk;
#pragma unroll
    for (int j = 0; j < 8; ++j)
        pk[j] = (short)f2b(W[(size_t)(kt * 32 + quad * 8 + j) * N + nt * 16 + m]);
    *(short8*)(out + (size_t)tid * 8) = pk;
}

__global__ void k_prep(const float* __restrict__ x, const float* __restrict__ isd,
                       unsigned int* __restrict__ xq, float* __restrict__ pooled,
                       const float* __restrict__ W1, unsigned short* __restrict__ w1z,
                       const float* __restrict__ W2, unsigned short* __restrict__ w2z,
                       int total4) {
    int i = blockIdx.x * blockDim.x + threadIdx.x;
    if (i < 128) pooled[i] = 0.f;
    if (i < 4096) wswz_one(W1, w1z, 256, i);                 // 128x256
    else if (i < 8192) wswz_one(W2, w2z, 128, i - 4096);     // 256x128
    if (i >= total4) return;
    float w = isd[i >> 5] * 16.f;
    float4 v = ((const float4*)x)[i];
    unsigned int u = __builtin_amdgcn_cvt_pk_fp8_f32(v.x * w, v.y * w, 0u, false);
    u = __builtin_amdgcn_cvt_pk_fp8_f32(v.z * w, v.w * w, u, true);
    xq[i] = u;
}

// ---------------- layer-1 aggregation -> bf16 rows ----------------

__global__ __launch_bounds__(256) void k_agg1(const unsigned int* __restrict__ Xq32,
                                              const int* __restrict__ off,
                                              const unsigned short* __restrict__ csr,
                                              const float* __restrict__ isd,
                                              uint2* __restrict__ out, int n) {
    int wid  = (blockIdx.x * 256 + threadIdx.x) >> 6;        // one wave per node
    int lane = threadIdx.x & 63;
    if (wid >= n) return;
    int half = lane >> 5, lp = lane & 31;
    int beg = off[wid], end = off[wid + 1];
    float a[4];
    gather_node(Xq32, csr, beg, end, wid, half, lp, a);
    if (half == 0) {
        float sc = isd[wid] * 0.0625f;                       // undo x16 fp8 scale
        uint2 o;
        o.x = f2b(a[0] * sc) | (f2b(a[1] * sc) << 16);
        o.y = f2b(a[2] * sc) | (f2b(a[3] * sc) << 16);
        out[(size_t)wid * 32 + lp] = o;
    }
}

// ---------------- fused GEMM1+GEMM2 ----------------
// stage1: h1 = relu(A@W1 + b1) -> LDS; stage2: t2q = fp8(16*isd*(h1@W2))

__global__ __launch_bounds__(256) void k_gemm12(const unsigned short* __restrict__ A,
                                                const unsigned short* __restrict__ W1z,
                                                const float* __restrict__ b1,
                                                const unsigned short* __restrict__ W2z,
                                                const float* __restrict__ isd,
                                                unsigned char* __restrict__ t2q, int M) {
    __shared__ unsigned short h1s[64 * 272];     // 64 rows x 256 cols, stride 272
    int tid = threadIdx.x;
    int lane = tid & 63, wm = tid >> 6;
    int m = lane & 15, quad = lane >> 4;

    long arow = (long)blockIdx.x * 64 + wm * 16 + m;
    if (arow >= M) arow = M - 1;
    const short8* Ap  = (const short8*)(A + (size_t)arow * 128);
    const short8* W1p = (const short8*)W1z + lane;

    float4v acc1[16];
    float4v zero = {0.f, 0.f, 0.f, 0.f};
#pragma unroll
    for (int nt = 0; nt < 16; ++nt) acc1[nt] = zero;
#pragma unroll
    for (int kt = 0; kt < 4; ++kt) {
        short8 a = Ap[kt * 4 + quad];
#pragma unroll
        for (int nt = 0; nt < 16; ++nt)
            acc1[nt] = __builtin_amdgcn_mfma_f32_16x16x32_bf16(a, W1p[(kt * 16 + nt) * 64],
                                                               acc1[nt], 0, 0, 0);
    }
    int r0 = wm * 16 + quad * 4;                 // block-local rows
#pragma unroll
    for (int nt = 0; nt < 16; ++nt) {
        int col = nt * 16 + m;
        float bz = b1[col];
#pragma unroll
        for (int reg = 0; reg < 4; ++reg) {
            float v = fmaxf(acc1[nt][reg] + bz, 0.f);
            h1s[(r0 + reg) * 272 + col] = (unsigned short)f2b(v);
        }
    }
    __syncthreads();

    float4v acc2[8];
#pragma unroll
    for (int nt = 0; nt < 8; ++nt) acc2[nt] = zero;
    const short8* W2p = (const short8*)W2z + lane;
    int rloc = wm * 16 + m;
#pragma unroll
    for (int kt = 0; kt < 8; ++kt) {
        short8 a2 = *(const short8*)(h1s + rloc * 272 + kt * 32 + quad * 8);
#pragma unroll
        for (int nt = 0; nt < 8; ++nt)
            acc2[nt] = __builtin_amdgcn_mfma_f32_16x16x32_bf16(a2, W2p[(kt * 8 + nt) * 64],
                                                               acc2[nt], 0, 0, 0);
    }
    int gr0 = blockIdx.x * 64 + wm * 16 + quad * 4;
    float sc[4];
#pragma unroll
    for (int reg = 0; reg < 4; ++reg) {
        int r = gr0 + reg;
        sc[reg] = ((r < M) ? isd[r] : 0.f) * 16.f;
    }
#pragma unroll
    for (int nt = 0; nt < 8; ++nt) {
        int col = nt * 16 + m;
#pragma unroll
        for (int reg = 0; reg < 4; ++reg) {
            int gr = gr0 + reg;
            if (gr < M) {
                float v = acc2[nt][reg] * sc[reg];
                unsigned int b = __builtin_amdgcn_cvt_pk_fp8_f32(v, v, 0u, false);
                t2q[(size_t)gr * 128 + col] = (unsigned char)(b & 0xffu);
            }
        }
    }
}

// ---------------- layer-2 aggregation: one node/wave, block partial ---------

__global__ __launch_bounds__(256) void k_agg2(const unsigned int* __restrict__ Xq32,
                                              const int* __restrict__ off,
                                              const unsigned short* __restrict__ csr,
                                              const float* __restrict__ isd,
                                              const float* __restrict__ b2,
                                              float* __restrict__ partial, int n) {
    __shared__ float sblk[128];
    int tid = threadIdx.x;
    if (tid < 128) sblk[tid] = 0.f;
    __syncthreads();
    int wid  = (blockIdx.x * 256 + tid) >> 6;                // one wave per node
    int lane = tid & 63;
    int half = lane >> 5, lp = lane & 31;
    if (wid < n) {
        int beg = off[wid], end = off[wid + 1];
        float a[4];
        gather_node(Xq32, csr, beg, end, wid, half, lp, a);
        if (half == 0) {
            float sc = isd[wid] * 0.0625f;
            atomicAdd(&sblk[4 * lp + 0], fmaxf(a[0] * sc + b2[4 * lp + 0], 0.f));
            atomicAdd(&sblk[4 * lp + 1], fmaxf(a[1] * sc + b2[4 * lp + 1], 0.f));
            atomicAdd(&sblk[4 * lp + 2], fmaxf(a[2] * sc + b2[4 * lp + 2], 0.f));
            atomicAdd(&sblk[4 * lp + 3], fmaxf(a[3] * sc + b2[4 * lp + 3], 0.f));
        }
    }
    __syncthreads();
    if (tid < 128) partial[(size_t)blockIdx.x * 128 + tid] = sblk[tid];
}

// ---------------- pool partials + head ----------------

__global__ __launch_bounds__(256) void k_pool(const float* __restrict__ partial,
                                              float* __restrict__ pooled, int nrows) {
    __shared__ float s[256];
    int t = threadIdx.x;
    int f = t & 127, rg = t >> 7;
    float a = 0.f;
    for (int r = blockIdx.x * 2 + rg; r < nrows; r += 256)
        a += partial[(size_t)r * 128 + f];
    s[t] = a;
    __syncthreads();
    if (rg == 0) atomicAdd(&pooled[f], s[t] + s[t + 128]);
}

__global__ void k_final(const float* __restrict__ pooled,
                        const float* __restrict__ Wfc,
                        const float* __restrict__ bfc,
                        float* __restrict__ out, float invN) {
    __shared__ float s[128];
    int t = threadIdx.x;
    s[t] = pooled[t] * invN * Wfc[t];
    __syncthreads();
    for (int d = 64; d > 0; d >>= 1) {
        if (t < d) s[t] += s[t + d];
        __syncthreads();
    }
    if (t == 0) out[0] = s[0] + bfc[0];
}

// ---------------- launch ----------------

extern "C" void kernel_launch(void* const* d_in, const int* in_sizes, int n_in,
                              void* d_out, int out_size, void* d_ws, size_t ws_size,
                              hipStream_t stream) {
    const float* x   = (const float*)d_in[0];
    const int*   ei  = (const int*)d_in[1];
    const float* W1  = (const float*)d_in[2];
    const float* b1  = (const float*)d_in[3];
    const float* W2  = (const float*)d_in[4];
    const float* b2  = (const float*)d_in[5];
    const float* Wfc = (const float*)d_in[6];
    const float* bfc = (const float*)d_in[7];
    float* out = (float*)d_out;

    int N = in_sizes[0] / FEAT;     // 50000
    int E = in_sizes[1] / 2;        // 800000
    const int* src = ei;
    const int* dst = ei + E;

    int NW = (E + TILE - 1) / TILE;         // 196
    int B  = (N + 255) >> 8;                // 196

    char* p = (char*)d_ws;
    auto alloc = [&](size_t bytes) {
        char* r = p;
        p += (bytes + 255) & ~(size_t)255;
        return r;
    };
    int* cnt             = (int*)alloc((size_t)B * NW * 4);
    unsigned int* ebuf   = (unsigned int*)alloc((size_t)E * 4);
    unsigned short* csr  = (unsigned short*)alloc((size_t)E * 2);
    float* isd           = (float*)alloc((size_t)N * 4);
    int* off             = (int*)alloc((size_t)(N + 1) * 4);
    unsigned int* xq     = (unsigned int*)alloc((size_t)N * 32 * 4);   // fp8 x, x16*isd
    unsigned int* agg1b  = (unsigned int*)alloc((size_t)N * 64 * 4);   // bf16 agg1
    unsigned char* t2q   = (unsigned char*)alloc((size_t)N * 128);     // fp8 t2, x16*isd
    unsigned short* w1z  = (unsigned short*)alloc(128 * 256 * 2);
    unsigned short* w2z  = (unsigned short*)alloc(256 * 128 * 2);
    int nblk             = (N + 3) / 4;                                // agg blocks
    float* partial       = (float*)alloc((size_t)nblk * 128 * 4);
    float* pooled        = (float*)alloc(128 * 4);

    // --- CSR build ---
    k_p1<<<NW, 1024, 0, stream>>>(dst, cnt, E, B, NW);
    k_bscan<<<1, 1024, 0, stream>>>(cnt, B * NW);
    k_p3<<<NW, 1024, 0, stream>>>(src, dst, cnt, ebuf, E, B, NW);
    k_p4<<<B, 256, 0, stream>>>(ebuf, cnt, isd, off, csr, E, B, NW, N);

    // --- prep (fp8 cast + weight swizzles + pool zero) ---
    int total4 = N * FEAT / 4;
    k_prep<<<(total4 + 255) / 256, 256, 0, stream>>>(x, isd, xq, pooled,
                                                     W1, w1z, W2, w2z, total4);

    int gblk = (N + 63) / 64;

    // layer 1: aggregate(fp8) -> fused GEMM(128->256->128) -> t2q fp8
    k_agg1<<<nblk, 256, 0, stream>>>(xq, off, csr, isd, (uint2*)agg1b, N);
    k_gemm12<<<gblk, 256, 0, stream>>>((const unsigned short*)agg1b, w1z, b1, w2z, isd, t2q, N);

    // layer 2: aggregate(fp8) + bias/relu -> block partials -> pool -> head
    k_agg2<<<nblk, 256, 0, stream>>>(t2q == nullptr ? nullptr : (const unsigned int*)t2q,
                                     off, csr, isd, b2, partial, N);
    k_pool<<<128, 256, 0, stream>>>(partial, pooled, nblk);
    k_final<<<1, 128, 0, stream>>>(pooled, Wfc, bfc, out, 1.0f / (float)N);
}

// Round 10
// 264.839 us; speedup vs baseline: 1.0581x; 1.0581x over previous
//
#include <hip/hip_runtime.h>

// GCN: 2x GCNConv(sym-norm, self-loops) + mean-pool + linear head.
// Round 10: consolidation. Gather = round 7's proven shape (wave-uniform row,
// one ushort (2 fp8) per lane, unroll 8 -- 1 contiguous segment per load
// instruction; pair/subgroup variants measured 2x/11x slower). CSR build =
// round 8/9's widened version (256-node buckets, 196 blocks/stage). Merged
// prep. fp32 accumulation everywhere.

#define FEAT 128
#define TILE 4096    // edges per bucketing workgroup (k_p1/k_p3)
#define VPT  40      // bscan elems per thread (covers B*NW = 196*196)

typedef __attribute__((ext_vector_type(8))) short short8;    // 8 bf16
typedef __attribute__((ext_vector_type(4))) float float4v;   // 4 fp32 acc
typedef __attribute__((ext_vector_type(2))) float floatx2;

__device__ __forceinline__ unsigned int f2b(float f) {       // rne bf16 (as uint)
    unsigned int u = __float_as_uint(f);
    return (u + 0x7fffu + ((u >> 16) & 1u)) >> 16;
}
__device__ __forceinline__ float b_lo(unsigned int u) { return __uint_as_float(u << 16); }
__device__ __forceinline__ float b_hi(unsigned int u) { return __uint_as_float(u & 0xffff0000u); }

// ---------------- bucketed CSR build (bucket = dst>>8, 256 nodes) -----------

__global__ __launch_bounds__(1024) void k_p1(const int* __restrict__ dst,
                                             int* __restrict__ cnt, int E, int B, int NW) {
    __shared__ int h[256];
    int t = threadIdx.x, w = blockIdx.x;
    if (t < 256) h[t] = 0;
    __syncthreads();
    int e0 = w * TILE, e1 = min(e0 + TILE, E);
    for (int e = e0 + t; e < e1; e += 1024) atomicAdd(&h[dst[e] >> 8], 1);
    __syncthreads();
    if (t < B) cnt[t * NW + w] = h[t];      // bucket-major
}

__global__ __launch_bounds__(1024) void k_bscan(int* __restrict__ cnt, int L) {
    __shared__ int s[1024];
    int t = threadIdx.x;
    int v[VPT]; int sum = 0;
#pragma unroll
    for (int j = 0; j < VPT; ++j) {
        int idx = t * VPT + j;
        int x = (idx < L) ? cnt[idx] : 0;
        v[j] = sum; sum += x;
    }
    s[t] = sum;
    __syncthreads();
    for (int d = 1; d < 1024; d <<= 1) {
        int x = (t >= d) ? s[t - d] : 0;
        __syncthreads();
        s[t] += x;
        __syncthreads();
    }
    int pre = (t > 0) ? s[t - 1] : 0;
#pragma unroll
    for (int j = 0; j < VPT; ++j) {
        int idx = t * VPT + j;
        if (idx < L) cnt[idx] = pre + v[j];
    }
}

__global__ __launch_bounds__(1024) void k_p3(const int* __restrict__ src,
                                             const int* __restrict__ dst,
                                             const int* __restrict__ cnt,
                                             unsigned int* __restrict__ ebuf,
                                             int E, int B, int NW) {
    __shared__ int cur[256];
    int t = threadIdx.x, w = blockIdx.x;
    if (t < B) cur[t] = cnt[t * NW + w];
    __syncthreads();
    int e0 = w * TILE, e1 = min(e0 + TILE, E);
    for (int e = e0 + t; e < e1; e += 1024) {
        int d = dst[e], s = src[e];
        int p = atomicAdd(&cur[d >> 8], 1);
        ebuf[p] = ((unsigned int)d << 16) | (unsigned int)s;
    }
}

// per bucket: histogram -> isd, intra-bucket scan -> off, scatter -> csr
__global__ __launch_bounds__(256) void k_p4(const unsigned int* __restrict__ ebuf,
                                            const int* __restrict__ cnt,
                                            float* __restrict__ isd,
                                            int* __restrict__ off,
                                            unsigned short* __restrict__ csr,
                                            int E, int B, int NW, int N) {
    __shared__ int h[256], s[256], cur[256];
    int t = threadIdx.x, b = blockIdx.x;
    h[t] = 0;
    __syncthreads();
    int s0 = cnt[b * NW];
    int s1e = (b + 1 < B) ? cnt[(b + 1) * NW] : E;
    for (int e = s0 + t; e < s1e; e += 256)
        atomicAdd(&h[(ebuf[e] >> 16) & 255], 1);
    __syncthreads();
    int own = h[t];
    s[t] = own;
    __syncthreads();
    for (int d = 1; d < 256; d <<= 1) {
        int x = (t >= d) ? s[t - d] : 0;
        __syncthreads();
        s[t] += x;
        __syncthreads();
    }
    int node = (b << 8) + t;
    int myoff = s0 + s[t] - own;
    cur[t] = myoff;
    if (node < N) {
        isd[node] = rsqrtf((float)(own + 1));        // +1 self-loop
        off[node] = myoff;
        if (node == N - 1) off[N] = s0 + s[t];       // == E
    }
    __syncthreads();
    for (int e = s0 + t; e < s1e; e += 256) {
        unsigned int v = ebuf[e];
        int p = atomicAdd(&cur[(v >> 16) & 255], 1);
        csr[p] = (unsigned short)(v & 0xffffu);
    }
}

// ---------------- prep: x->fp8 scaled, weight swizzles, pool zero -----------

__device__ __forceinline__ void wswz_one(const float* W, unsigned short* out,
                                         int N, int tid) {
    int lane = tid & 63, f = tid >> 6;
    int NT = N >> 4;
    int nt = f % NT, kt = f / NT;
    int m = lane & 15, quad = lane >> 4;
    short8 pk;
#pragma unroll
    for (int j = 0; j < 8; ++j)
        pk[j] = (short)f2b(W[(size_t)(kt * 32 + quad * 8 + j) * N + nt * 16 + m]);
    *(short8*)(out + (size_t)tid * 8) = pk;
}

__global__ void k_prep(const float* __restrict__ x, const float* __restrict__ isd,
                       unsigned int* __restrict__ xq, float* __restrict__ pooled,
                       const float* __restrict__ W1, unsigned short* __restrict__ w1z,
                       const float* __restrict__ W2, unsigned short* __restrict__ w2z,
                       int total4) {
    int i = blockIdx.x * blockDim.x + threadIdx.x;
    if (i < 128) pooled[i] = 0.f;
    if (i < 4096) wswz_one(W1, w1z, 256, i);                 // 128x256
    else if (i < 8192) wswz_one(W2, w2z, 128, i - 4096);     // 256x128
    if (i >= total4) return;
    float w = isd[i >> 5] * 16.f;
    float4 v = ((const float4*)x)[i];
    unsigned int u = __builtin_amdgcn_cvt_pk_fp8_f32(v.x * w, v.y * w, 0u, false);
    u = __builtin_amdgcn_cvt_pk_fp8_f32(v.z * w, v.w * w, u, true);
    xq[i] = u;
}

// ---------------- aggregation (whole wave per node, fp8 rows) ---------------
// out[n] = bf16( isd[n]/16 * (sum_{s in N(n)} Xs[s] + Xs[n]) ), Xs = fp8(16*isd*X)
// lane owns feats {2*lane, 2*lane+1}: one ushort (2 fp8) per row -- the wave's
// access is one contiguous 128B segment (proven fastest shape).

__global__ __launch_bounds__(256) void k_agg(const unsigned short* __restrict__ Xq,
                                             const int* __restrict__ off,
                                             const unsigned short* __restrict__ csr,
                                             const float* __restrict__ isd,
                                             unsigned int* __restrict__ out, int n) {
    int wid  = (blockIdx.x * 256 + threadIdx.x) >> 6;
    int lane = threadIdx.x & 63;
    if (wid >= n) return;
    wid = __builtin_amdgcn_readfirstlane(wid);           // wave-uniform
    int beg = off[wid], end = off[wid + 1];
    float a0, a1;
    {
        unsigned int q = Xq[(size_t)wid * 64 + lane];    // self term
        floatx2 f = __builtin_amdgcn_cvt_pk_f32_fp8(q, false);
        a0 = f[0]; a1 = f[1];
    }
    int e = beg;
    for (; e + 8 <= end; e += 8) {                       // 8 gathers in flight
        int s0 = csr[e],     s1 = csr[e + 1], s2 = csr[e + 2], s3 = csr[e + 3];
        int s4 = csr[e + 4], s5 = csr[e + 5], s6 = csr[e + 6], s7 = csr[e + 7];
        unsigned int q0 = Xq[(size_t)s0 * 64 + lane];
        unsigned int q1 = Xq[(size_t)s1 * 64 + lane];
        unsigned int q2 = Xq[(size_t)s2 * 64 + lane];
        unsigned int q3 = Xq[(size_t)s3 * 64 + lane];
        unsigned int q4 = Xq[(size_t)s4 * 64 + lane];
        unsigned int q5 = Xq[(size_t)s5 * 64 + lane];
        unsigned int q6 = Xq[(size_t)s6 * 64 + lane];
        unsigned int q7 = Xq[(size_t)s7 * 64 + lane];
        floatx2 f0 = __builtin_amdgcn_cvt_pk_f32_fp8(q0, false);
        floatx2 f1 = __builtin_amdgcn_cvt_pk_f32_fp8(q1, false);
        floatx2 f2 = __builtin_amdgcn_cvt_pk_f32_fp8(q2, false);
        floatx2 f3 = __builtin_amdgcn_cvt_pk_f32_fp8(q3, false);
        floatx2 f4 = __builtin_amdgcn_cvt_pk_f32_fp8(q4, false);
        floatx2 f5 = __builtin_amdgcn_cvt_pk_f32_fp8(q5, false);
        floatx2 f6 = __builtin_amdgcn_cvt_pk_f32_fp8(q6, false);
        floatx2 f7 = __builtin_amdgcn_cvt_pk_f32_fp8(q7, false);
        a0 += f0[0] + f1[0] + f2[0] + f3[0] + f4[0] + f5[0] + f6[0] + f7[0];
        a1 += f0[1] + f1[1] + f2[1] + f3[1] + f4[1] + f5[1] + f6[1] + f7[1];
    }
    for (; e + 2 <= end; e += 2) {
        int s0 = csr[e], s1 = csr[e + 1];
        unsigned int q0 = Xq[(size_t)s0 * 64 + lane];
        unsigned int q1 = Xq[(size_t)s1 * 64 + lane];
        floatx2 f0 = __builtin_amdgcn_cvt_pk_f32_fp8(q0, false);
        floatx2 f1 = __builtin_amdgcn_cvt_pk_f32_fp8(q1, false);
        a0 += f0[0] + f1[0];
        a1 += f0[1] + f1[1];
    }
    if (e < end) {
        unsigned int q0 = Xq[(size_t)csr[e] * 64 + lane];
        floatx2 f0 = __builtin_amdgcn_cvt_pk_f32_fp8(q0, false);
        a0 += f0[0];
        a1 += f0[1];
    }
    float wn = isd[wid] * 0.0625f;                       // undo the x16 fp8 scale
    out[(size_t)wid * 64 + lane] = f2b(wn * a0) | (f2b(wn * a1) << 16);
}

// ---------------- fused GEMM1+GEMM2 ----------------
// stage1: h1 = relu(A@W1 + b1) -> LDS; stage2: t2q = fp8(16*isd*(h1@W2))

__global__ __launch_bounds__(256) void k_gemm12(const unsigned short* __restrict__ A,
                                                const unsigned short* __restrict__ W1z,
                                                const float* __restrict__ b1,
                                                const unsigned short* __restrict__ W2z,
                                                const float* __restrict__ isd,
                                                unsigned char* __restrict__ t2q, int M) {
    __shared__ unsigned short h1s[64 * 272];     // 64 rows x 256 cols, stride 272
    int tid = threadIdx.x;
    int lane = tid & 63, wm = tid >> 6;
    int m = lane & 15, quad = lane >> 4;

    long arow = (long)blockIdx.x * 64 + wm * 16 + m;
    if (arow >= M) arow = M - 1;
    const short8* Ap  = (const short8*)(A + (size_t)arow * 128);
    const short8* W1p = (const short8*)W1z + lane;

    float4v acc1[16];
    float4v zero = {0.f, 0.f, 0.f, 0.f};
#pragma unroll
    for (int nt = 0; nt < 16; ++nt) acc1[nt] = zero;
#pragma unroll
    for (int kt = 0; kt < 4; ++kt) {
        short8 a = Ap[kt * 4 + quad];
#pragma unroll
        for (int nt = 0; nt < 16; ++nt)
            acc1[nt] = __builtin_amdgcn_mfma_f32_16x16x32_bf16(a, W1p[(kt * 16 + nt) * 64],
                                                               acc1[nt], 0, 0, 0);
    }
    int r0 = wm * 16 + quad * 4;                 // block-local rows
#pragma unroll
    for (int nt = 0; nt < 16; ++nt) {
        int col = nt * 16 + m;
        float bz = b1[col];
#pragma unroll
        for (int reg = 0; reg < 4; ++reg) {
            float v = fmaxf(acc1[nt][reg] + bz, 0.f);
            h1s[(r0 + reg) * 272 + col] = (unsigned short)f2b(v);
        }
    }
    __syncthreads();

    float4v acc2[8];
#pragma unroll
    for (int nt = 0; nt < 8; ++nt) acc2[nt] = zero;
    const short8* W2p = (const short8*)W2z + lane;
    int rloc = wm * 16 + m;
#pragma unroll
    for (int kt = 0; kt < 8; ++kt) {
        short8 a2 = *(const short8*)(h1s + rloc * 272 + kt * 32 + quad * 8);
#pragma unroll
        for (int nt = 0; nt < 8; ++nt)
            acc2[nt] = __builtin_amdgcn_mfma_f32_16x16x32_bf16(a2, W2p[(kt * 8 + nt) * 64],
                                                               acc2[nt], 0, 0, 0);
    }
    int gr0 = blockIdx.x * 64 + wm * 16 + quad * 4;
    float sc[4];
#pragma unroll
    for (int reg = 0; reg < 4; ++reg) {
        int r = gr0 + reg;
        sc[reg] = ((r < M) ? isd[r] : 0.f) * 16.f;
    }
#pragma unroll
    for (int nt = 0; nt < 8; ++nt) {
        int col = nt * 16 + m;
#pragma unroll
        for (int reg = 0; reg < 4; ++reg) {
            int gr = gr0 + reg;
            if (gr < M) {
                float v = acc2[nt][reg] * sc[reg];
                unsigned int b = __builtin_amdgcn_cvt_pk_fp8_f32(v, v, 0u, false);
                t2q[(size_t)gr * 128 + col] = (unsigned char)(b & 0xffu);
            }
        }
    }
}

// ---------------- pool: pooled[f] += sum_n relu(agg2[n][f] + b2[f])

__global__ __launch_bounds__(256) void k_post(const unsigned int* __restrict__ agg2,
                                              const float* __restrict__ b2,
                                              float* __restrict__ pooled, int n) {
    __shared__ float s0[256], s1[256];
    int f2 = threadIdx.x & 63;       // feature pair
    int rg = threadIdx.x >> 6;       // 0..3 rows in flight
    float bz0 = b2[2 * f2], bz1 = b2[2 * f2 + 1];
    float a0 = 0.f, a1 = 0.f;
    for (int r = blockIdx.x * 4 + rg; r < n; r += gridDim.x * 4) {
        unsigned int u = agg2[(size_t)r * 64 + f2];
        a0 += fmaxf(b_lo(u) + bz0, 0.f);
        a1 += fmaxf(b_hi(u) + bz1, 0.f);
    }
    s0[threadIdx.x] = a0;
    s1[threadIdx.x] = a1;
    __syncthreads();
    if (rg == 0) {
        float t0 = s0[f2] + s0[64 + f2] + s0[128 + f2] + s0[192 + f2];
        float t1 = s1[f2] + s1[64 + f2] + s1[128 + f2] + s1[192 + f2];
        atomicAdd(&pooled[2 * f2], t0);
        atomicAdd(&pooled[2 * f2 + 1], t1);
    }
}

__global__ void k_final(const float* __restrict__ pooled,
                        const float* __restrict__ Wfc,
                        const float* __restrict__ bfc,
                        float* __restrict__ out, float invN) {
    __shared__ float s[128];
    int t = threadIdx.x;
    s[t] = pooled[t] * invN * Wfc[t];
    __syncthreads();
    for (int d = 64; d > 0; d >>= 1) {
        if (t < d) s[t] += s[t + d];
        __syncthreads();
    }
    if (t == 0) out[0] = s[0] + bfc[0];
}

// ---------------- launch ----------------

extern "C" void kernel_launch(void* const* d_in, const int* in_sizes, int n_in,
                              void* d_out, int out_size, void* d_ws, size_t ws_size,
                              hipStream_t stream) {
    const float* x   = (const float*)d_in[0];
    const int*   ei  = (const int*)d_in[1];
    const float* W1  = (const float*)d_in[2];
    const float* b1  = (const float*)d_in[3];
    const float* W2  = (const float*)d_in[4];
    const float* b2  = (const float*)d_in[5];
    const float* Wfc = (const float*)d_in[6];
    const float* bfc = (const float*)d_in[7];
    float* out = (float*)d_out;

    int N = in_sizes[0] / FEAT;     // 50000
    int E = in_sizes[1] / 2;        // 800000
    const int* src = ei;
    const int* dst = ei + E;

    int NW = (E + TILE - 1) / TILE;         // 196
    int B  = (N + 255) >> 8;                // 196

    char* p = (char*)d_ws;
    auto alloc = [&](size_t bytes) {
        char* r = p;
        p += (bytes + 255) & ~(size_t)255;
        return r;
    };
    int* cnt             = (int*)alloc((size_t)B * NW * 4);
    unsigned int* ebuf   = (unsigned int*)alloc((size_t)E * 4);
    unsigned short* csr  = (unsigned short*)alloc((size_t)E * 2);
    float* isd           = (float*)alloc((size_t)N * 4);
    int* off             = (int*)alloc((size_t)(N + 1) * 4);
    unsigned int* xq     = (unsigned int*)alloc((size_t)N * 32 * 4);   // fp8 x, x16*isd
    unsigned int* agg1b  = (unsigned int*)alloc((size_t)N * 64 * 4);   // bf16 agg1
    unsigned char* t2q   = (unsigned char*)alloc((size_t)N * 128);     // fp8 t2, x16*isd
    unsigned int* ag2b   = (unsigned int*)alloc((size_t)N * 64 * 4);   // bf16 agg2
    unsigned short* w1z  = (unsigned short*)alloc(128 * 256 * 2);
    unsigned short* w2z  = (unsigned short*)alloc(256 * 128 * 2);
    float* pooled        = (float*)alloc(128 * 4);

    // --- CSR build (widened: 196 blocks per stage) ---
    k_p1<<<NW, 1024, 0, stream>>>(dst, cnt, E, B, NW);
    k_bscan<<<1, 1024, 0, stream>>>(cnt, B * NW);
    k_p3<<<NW, 1024, 0, stream>>>(src, dst, cnt, ebuf, E, B, NW);
    k_p4<<<B, 256, 0, stream>>>(ebuf, cnt, isd, off, csr, E, B, NW, N);

    // --- prep (fp8 cast + weight swizzles + pool zero) ---
    int total4 = N * FEAT / 4;
    k_prep<<<(total4 + 255) / 256, 256, 0, stream>>>(x, isd, xq, pooled,
                                                     W1, w1z, W2, w2z, total4);

    int gblk = (N + 63) / 64;
    int nblk = (N + 3) / 4;

    // layer 1: aggregate(fp8) -> fused GEMM(128->256->128) -> t2q fp8
    k_agg<<<nblk, 256, 0, stream>>>((const unsigned short*)xq, off, csr, isd, agg1b, N);
    k_gemm12<<<gblk, 256, 0, stream>>>((const unsigned short*)agg1b, w1z, b1, w2z, isd, t2q, N);

    // layer 2: aggregate(fp8) -> (+b2, relu, pool)
    k_agg<<<nblk, 256, 0, stream>>>((const unsigned short*)t2q, off, csr, isd, ag2b, N);
    k_post<<<512, 256, 0, stream>>>(ag2b, b2, pooled, N);
    k_final<<<1, 128, 0, stream>>>(pooled, Wfc, bfc, out, 1.0f / (float)N);
}

// Round 11
// 214.986 us; speedup vs baseline: 1.3034x; 1.2319x over previous
//
#include <hip/hip_runtime.h>

// GCN: 2x GCNConv(sym-norm, self-loops) + mean-pool + linear head.
// Round 11: round-7 CSR config restored (the round-8 "widening" was a ~19us
// regression, mis-attributed); round-7 wave-uniform fp8 gather untouched;
// layer-2 agg epilogue now fuses bias+relu+pool (64-replica atomics),
// deleting ag2b + k_post. 9 dispatches.

#define FEAT 128
#define TILE 16384   // edges per bucketing workgroup (round-7 config)
#define VPT  3       // bscan elems per thread (covers B*NW = 49*49)

typedef __attribute__((ext_vector_type(8))) short short8;    // 8 bf16
typedef __attribute__((ext_vector_type(4))) float float4v;   // 4 fp32 acc
typedef __attribute__((ext_vector_type(2))) float floatx2;

__device__ __forceinline__ unsigned int f2b(float f) {       // rne bf16 (as uint)
    unsigned int u = __float_as_uint(f);
    return (u + 0x7fffu + ((u >> 16) & 1u)) >> 16;
}

// ---------------- bucketed CSR build (bucket = dst>>10, 1024 nodes) ---------

__global__ __launch_bounds__(1024) void k_p1(const int* __restrict__ dst,
                                             int* __restrict__ cnt, int E, int B, int NW) {
    __shared__ int h[64];
    int t = threadIdx.x, w = blockIdx.x;
    if (t < B) h[t] = 0;
    __syncthreads();
    int e0 = w * TILE, e1 = min(e0 + TILE, E);
    for (int e = e0 + t; e < e1; e += 1024) atomicAdd(&h[dst[e] >> 10], 1);
    __syncthreads();
    if (t < B) cnt[t * NW + w] = h[t];      // bucket-major
}

__global__ __launch_bounds__(1024) void k_bscan(int* __restrict__ cnt, int L) {
    __shared__ int s[1024];
    int t = threadIdx.x;
    int v[VPT]; int sum = 0;
#pragma unroll
    for (int j = 0; j < VPT; ++j) {
        int idx = t * VPT + j;
        int x = (idx < L) ? cnt[idx] : 0;
        v[j] = sum; sum += x;
    }
    s[t] = sum;
    __syncthreads();
    for (int d = 1; d < 1024; d <<= 1) {
        int x = (t >= d) ? s[t - d] : 0;
        __syncthreads();
        s[t] += x;
        __syncthreads();
    }
    int pre = (t > 0) ? s[t - 1] : 0;
#pragma unroll
    for (int j = 0; j < VPT; ++j) {
        int idx = t * VPT + j;
        if (idx < L) cnt[idx] = pre + v[j];
    }
}

__global__ __launch_bounds__(1024) void k_p3(const int* __restrict__ src,
                                             const int* __restrict__ dst,
                                             const int* __restrict__ cnt,
                                             unsigned int* __restrict__ ebuf,
                                             int E, int B, int NW) {
    __shared__ int cur[64];
    int t = threadIdx.x, w = blockIdx.x;
    if (t < B) cur[t] = cnt[t * NW + w];
    __syncthreads();
    int e0 = w * TILE, e1 = min(e0 + TILE, E);
    for (int e = e0 + t; e < e1; e += 1024) {
        int d = dst[e], s = src[e];
        int p = atomicAdd(&cur[d >> 10], 1);
        ebuf[p] = ((unsigned int)d << 16) | (unsigned int)s;
    }
}

// merged: per bucket histogram -> isd, intra-bucket scan -> off, scatter -> csr
__global__ __launch_bounds__(1024) void k_p4(const unsigned int* __restrict__ ebuf,
                                             const int* __restrict__ cnt,
                                             float* __restrict__ isd,
                                             int* __restrict__ off,
                                             unsigned short* __restrict__ csr,
                                             int E, int B, int NW, int N) {
    __shared__ int h[1024];
    __shared__ int s[1024];
    __shared__ int cur[1024];
    int t = threadIdx.x, b = blockIdx.x;
    h[t] = 0;
    __syncthreads();
    int s0 = cnt[b * NW];
    int s1 = (b + 1 < B) ? cnt[(b + 1) * NW] : E;
    for (int e = s0 + t; e < s1; e += 1024)
        atomicAdd(&h[(ebuf[e] >> 16) & 1023], 1);
    __syncthreads();
    int own = h[t];
    s[t] = own;
    __syncthreads();
    for (int d = 1; d < 1024; d <<= 1) {
        int x = (t >= d) ? s[t - d] : 0;
        __syncthreads();
        s[t] += x;
        __syncthreads();
    }
    int node = (b << 10) + t;
    int myoff = s0 + s[t] - own;
    cur[t] = myoff;
    if (node < N) {
        isd[node] = rsqrtf((float)(own + 1));        // +1 self-loop
        off[node] = myoff;
        if (node == N - 1) off[N] = s0 + s[t];       // == E
    }
    __syncthreads();
    for (int e = s0 + t; e < s1; e += 1024) {
        unsigned int v = ebuf[e];
        int p = atomicAdd(&cur[(v >> 16) & 1023], 1);
        csr[p] = (unsigned short)(v & 0xffffu);
    }
}

// ---------------- prep: x->fp8 scaled, weight swizzles, pool zero -----------

__device__ __forceinline__ void wswz_one(const float* W, unsigned short* out,
                                         int N, int tid) {
    int lane = tid & 63, f = tid >> 6;
    int NT = N >> 4;
    int nt = f % NT, kt = f / NT;
    int m = lane & 15, quad = lane >> 4;
    short8 pk;
#pragma unroll
    for (int j = 0; j < 8; ++j)
        pk[j] = (short)f2b(W[(size_t)(kt * 32 + quad * 8 + j) * N + nt * 16 + m]);
    *(short8*)(out + (size_t)tid * 8) = pk;
}

__global__ void k_prep(const float* __restrict__ x, const float* __restrict__ isd,
                       unsigned int* __restrict__ xq, float* __restrict__ pooled,
                       const float* __restrict__ W1, unsigned short* __restrict__ w1z,
                       const float* __restrict__ W2, unsigned short* __restrict__ w2z,
                       int total4) {
    int i = blockIdx.x * blockDim.x + threadIdx.x;
    if (i < 8192) pooled[i] = 0.f;                           // 64 replicas x 128
    if (i < 4096) wswz_one(W1, w1z, 256, i);                 // 128x256
    else if (i < 8192) wswz_one(W2, w2z, 128, i - 4096);     // 256x128
    if (i >= total4) return;
    float w = isd[i >> 5] * 16.f;
    float4 v = ((const float4*)x)[i];
    unsigned int u = __builtin_amdgcn_cvt_pk_fp8_f32(v.x * w, v.y * w, 0u, false);
    u = __builtin_amdgcn_cvt_pk_fp8_f32(v.z * w, v.w * w, u, true);
    xq[i] = u;
}

// ---------------- gather core (round-7 shape, untouched) --------------------
// lane owns feats {2*lane, 2*lane+1}: one ushort (2 fp8) per row; the wave's
// access is one contiguous 128B segment (proven fastest shape; 2-seg = 2x,
// 8-seg = 11x slower). Unroll 8.

__device__ __forceinline__ void gather_row(const unsigned short* __restrict__ Xq,
                                           const int* __restrict__ off,
                                           const unsigned short* __restrict__ csr,
                                           int wid, int lane, float& ra0, float& ra1) {
    int beg = off[wid], end = off[wid + 1];
    float a0, a1;
    {
        unsigned int q = Xq[(size_t)wid * 64 + lane];    // self term
        floatx2 f = __builtin_amdgcn_cvt_pk_f32_fp8(q, false);
        a0 = f[0]; a1 = f[1];
    }
    int e = beg;
    for (; e + 8 <= end; e += 8) {                       // 8 gathers in flight
        int s0 = csr[e],     s1 = csr[e + 1], s2 = csr[e + 2], s3 = csr[e + 3];
        int s4 = csr[e + 4], s5 = csr[e + 5], s6 = csr[e + 6], s7 = csr[e + 7];
        unsigned int q0 = Xq[(size_t)s0 * 64 + lane];
        unsigned int q1 = Xq[(size_t)s1 * 64 + lane];
        unsigned int q2 = Xq[(size_t)s2 * 64 + lane];
        unsigned int q3 = Xq[(size_t)s3 * 64 + lane];
        unsigned int q4 = Xq[(size_t)s4 * 64 + lane];
        unsigned int q5 = Xq[(size_t)s5 * 64 + lane];
        unsigned int q6 = Xq[(size_t)s6 * 64 + lane];
        unsigned int q7 = Xq[(size_t)s7 * 64 + lane];
        floatx2 f0 = __builtin_amdgcn_cvt_pk_f32_fp8(q0, false);
        floatx2 f1 = __builtin_amdgcn_cvt_pk_f32_fp8(q1, false);
        floatx2 f2 = __builtin_amdgcn_cvt_pk_f32_fp8(q2, false);
        floatx2 f3 = __builtin_amdgcn_cvt_pk_f32_fp8(q3, false);
        floatx2 f4 = __builtin_amdgcn_cvt_pk_f32_fp8(q4, false);
        floatx2 f5 = __builtin_amdgcn_cvt_pk_f32_fp8(q5, false);
        floatx2 f6 = __builtin_amdgcn_cvt_pk_f32_fp8(q6, false);
        floatx2 f7 = __builtin_amdgcn_cvt_pk_f32_fp8(q7, false);
        a0 += f0[0] + f1[0] + f2[0] + f3[0] + f4[0] + f5[0] + f6[0] + f7[0];
        a1 += f0[1] + f1[1] + f2[1] + f3[1] + f4[1] + f5[1] + f6[1] + f7[1];
    }
    for (; e + 2 <= end; e += 2) {
        int s0 = csr[e], s1 = csr[e + 1];
        unsigned int q0 = Xq[(size_t)s0 * 64 + lane];
        unsigned int q1 = Xq[(size_t)s1 * 64 + lane];
        floatx2 f0 = __builtin_amdgcn_cvt_pk_f32_fp8(q0, false);
        floatx2 f1 = __builtin_amdgcn_cvt_pk_f32_fp8(q1, false);
        a0 += f0[0] + f1[0];
        a1 += f0[1] + f1[1];
    }
    if (e < end) {
        unsigned int q0 = Xq[(size_t)csr[e] * 64 + lane];
        floatx2 f0 = __builtin_amdgcn_cvt_pk_f32_fp8(q0, false);
        a0 += f0[0];
        a1 += f0[1];
    }
    ra0 = a0; ra1 = a1;
}

// ---------------- layer-1 aggregation -> bf16 rows ----------------

__global__ __launch_bounds__(256) void k_agg1(const unsigned short* __restrict__ Xq,
                                              const int* __restrict__ off,
                                              const unsigned short* __restrict__ csr,
                                              const float* __restrict__ isd,
                                              unsigned int* __restrict__ out, int n) {
    int wid  = (blockIdx.x * 256 + threadIdx.x) >> 6;
    int lane = threadIdx.x & 63;
    if (wid >= n) return;
    wid = __builtin_amdgcn_readfirstlane(wid);           // wave-uniform
    float a0, a1;
    gather_row(Xq, off, csr, wid, lane, a0, a1);
    float wn = isd[wid] * 0.0625f;                       // undo the x16 fp8 scale
    out[(size_t)wid * 64 + lane] = f2b(wn * a0) | (f2b(wn * a1) << 16);
}

// ---------------- fused GEMM1+GEMM2 ----------------
// stage1: h1 = relu(A@W1 + b1) -> LDS; stage2: t2q = fp8(16*isd*(h1@W2))

__global__ __launch_bounds__(256) void k_gemm12(const unsigned short* __restrict__ A,
                                                const unsigned short* __restrict__ W1z,
                                                const float* __restrict__ b1,
                                                const unsigned short* __restrict__ W2z,
                                                const float* __restrict__ isd,
                                                unsigned char* __restrict__ t2q, int M) {
    __shared__ unsigned short h1s[64 * 272];     // 64 rows x 256 cols, stride 272
    int tid = threadIdx.x;
    int lane = tid & 63, wm = tid >> 6;
    int m = lane & 15, quad = lane >> 4;

    long arow = (long)blockIdx.x * 64 + wm * 16 + m;
    if (arow >= M) arow = M - 1;
    const short8* Ap  = (const short8*)(A + (size_t)arow * 128);
    const short8* W1p = (const short8*)W1z + lane;

    float4v acc1[16];
    float4v zero = {0.f, 0.f, 0.f, 0.f};
#pragma unroll
    for (int nt = 0; nt < 16; ++nt) acc1[nt] = zero;
#pragma unroll
    for (int kt = 0; kt < 4; ++kt) {
        short8 a = Ap[kt * 4 + quad];
#pragma unroll
        for (int nt = 0; nt < 16; ++nt)
            acc1[nt] = __builtin_amdgcn_mfma_f32_16x16x32_bf16(a, W1p[(kt * 16 + nt) * 64],
                                                               acc1[nt], 0, 0, 0);
    }
    int r0 = wm * 16 + quad * 4;                 // block-local rows
#pragma unroll
    for (int nt = 0; nt < 16; ++nt) {
        int col = nt * 16 + m;
        float bz = b1[col];
#pragma unroll
        for (int reg = 0; reg < 4; ++reg) {
            float v = fmaxf(acc1[nt][reg] + bz, 0.f);
            h1s[(r0 + reg) * 272 + col] = (unsigned short)f2b(v);
        }
    }
    __syncthreads();

    float4v acc2[8];
#pragma unroll
    for (int nt = 0; nt < 8; ++nt) acc2[nt] = zero;
    const short8* W2p = (const short8*)W2z + lane;
    int rloc = wm * 16 + m;
#pragma unroll
    for (int kt = 0; kt < 8; ++kt) {
        short8 a2 = *(const short8*)(h1s + rloc * 272 + kt * 32 + quad * 8);
#pragma unroll
        for (int nt = 0; nt < 8; ++nt)
            acc2[nt] = __builtin_amdgcn_mfma_f32_16x16x32_bf16(a2, W2p[(kt * 8 + nt) * 64],
                                                               acc2[nt], 0, 0, 0);
    }
    int gr0 = blockIdx.x * 64 + wm * 16 + quad * 4;
    float sc[4];
#pragma unroll
    for (int reg = 0; reg < 4; ++reg) {
        int r = gr0 + reg;
        sc[reg] = ((r < M) ? isd[r] : 0.f) * 16.f;
    }
#pragma unroll
    for (int nt = 0; nt < 8; ++nt) {
        int col = nt * 16 + m;
#pragma unroll
        for (int reg = 0; reg < 4; ++reg) {
            int gr = gr0 + reg;
            if (gr < M) {
                float v = acc2[nt][reg] * sc[reg];
                unsigned int b = __builtin_amdgcn_cvt_pk_fp8_f32(v, v, 0u, false);
                t2q[(size_t)gr * 128 + col] = (unsigned char)(b & 0xffu);
            }
        }
    }
}

// ------- layer-2 aggregation with fused bias/relu/pool epilogue -------------
// Same per-wave gather; epilogue: LDS reduce across the block's 4 waves,
// then 128 global atomics into a 64-replica pooled array (low contention).

__global__ __launch_bounds__(256) void k_agg2p(const unsigned short* __restrict__ Xq,
                                               const int* __restrict__ off,
                                               const unsigned short* __restrict__ csr,
                                               const float* __restrict__ isd,
                                               const float* __restrict__ b2,
                                               float* __restrict__ pooled, int n) {
    __shared__ float s0[256], s1[256];
    int tid = threadIdx.x;
    int wid  = (blockIdx.x * 256 + tid) >> 6;
    int lane = tid & 63;
    float r0 = 0.f, r1 = 0.f;
    if (wid < n) {
        int wu = __builtin_amdgcn_readfirstlane(wid);
        float a0, a1;
        gather_row(Xq, off, csr, wu, lane, a0, a1);
        float wn = isd[wu] * 0.0625f;
        r0 = fmaxf(wn * a0 + b2[2 * lane], 0.f);
        r1 = fmaxf(wn * a1 + b2[2 * lane + 1], 0.f);
    }
    s0[tid] = r0;
    s1[tid] = r1;
    __syncthreads();
    if (tid < 64) {
        float t0 = s0[tid] + s0[tid + 64] + s0[tid + 128] + s0[tid + 192];
        float t1 = s1[tid] + s1[tid + 64] + s1[tid + 128] + s1[tid + 192];
        float* dst = pooled + (blockIdx.x & 63) * 128;
        atomicAdd(&dst[2 * tid], t0);
        atomicAdd(&dst[2 * tid + 1], t1);
    }
}

// ---------------- head: sum 64 replicas, dot with Wfc ----------------

__global__ void k_final(const float* __restrict__ pooled,
                        const float* __restrict__ Wfc,
                        const float* __restrict__ bfc,
                        float* __restrict__ out, float invN) {
    __shared__ float s[128];
    int t = threadIdx.x;
    float v = 0.f;
#pragma unroll
    for (int r = 0; r < 64; ++r) v += pooled[r * 128 + t];
    s[t] = v * invN * Wfc[t];
    __syncthreads();
    for (int d = 64; d > 0; d >>= 1) {
        if (t < d) s[t] += s[t + d];
        __syncthreads();
    }
    if (t == 0) out[0] = s[0] + bfc[0];
}

// ---------------- launch ----------------

extern "C" void kernel_launch(void* const* d_in, const int* in_sizes, int n_in,
                              void* d_out, int out_size, void* d_ws, size_t ws_size,
                              hipStream_t stream) {
    const float* x   = (const float*)d_in[0];
    const int*   ei  = (const int*)d_in[1];
    const float* W1  = (const float*)d_in[2];
    const float* b1  = (const float*)d_in[3];
    const float* W2  = (const float*)d_in[4];
    const float* b2  = (const float*)d_in[5];
    const float* Wfc = (const float*)d_in[6];
    const float* bfc = (const float*)d_in[7];
    float* out = (float*)d_out;

    int N = in_sizes[0] / FEAT;     // 50000
    int E = in_sizes[1] / 2;        // 800000
    const int* src = ei;
    const int* dst = ei + E;

    int NW = (E + TILE - 1) / TILE;         // 49
    int B  = (N + 1023) >> 10;              // 49

    char* p = (char*)d_ws;
    auto alloc = [&](size_t bytes) {
        char* r = p;
        p += (bytes + 255) & ~(size_t)255;
        return r;
    };
    int* cnt             = (int*)alloc((size_t)B * NW * 4);
    unsigned int* ebuf   = (unsigned int*)alloc((size_t)E * 4);
    unsigned short* csr  = (unsigned short*)alloc((size_t)E * 2);
    float* isd           = (float*)alloc((size_t)N * 4);
    int* off             = (int*)alloc((size_t)(N + 1) * 4);
    unsigned int* xq     = (unsigned int*)alloc((size_t)N * 32 * 4);   // fp8 x, x16*isd
    unsigned int* agg1b  = (unsigned int*)alloc((size_t)N * 64 * 4);   // bf16 agg1
    unsigned char* t2q   = (unsigned char*)alloc((size_t)N * 128);     // fp8 t2, x16*isd
    unsigned short* w1z  = (unsigned short*)alloc(128 * 256 * 2);
    unsigned short* w2z  = (unsigned short*)alloc(256 * 128 * 2);
    float* pooled        = (float*)alloc(64 * 128 * 4);                // 64 replicas

    // --- CSR build (round-7 config) ---
    k_p1<<<NW, 1024, 0, stream>>>(dst, cnt, E, B, NW);
    k_bscan<<<1, 1024, 0, stream>>>(cnt, B * NW);
    k_p3<<<NW, 1024, 0, stream>>>(src, dst, cnt, ebuf, E, B, NW);
    k_p4<<<B, 1024, 0, stream>>>(ebuf, cnt, isd, off, csr, E, B, NW, N);

    // --- prep (fp8 cast + weight swizzles + pool zero) ---
    int total4 = N * FEAT / 4;
    k_prep<<<(total4 + 255) / 256, 256, 0, stream>>>(x, isd, xq, pooled,
                                                     W1, w1z, W2, w2z, total4);

    int gblk = (N + 63) / 64;
    int nblk = (N + 3) / 4;

    // layer 1: aggregate(fp8) -> fused GEMM(128->256->128) -> t2q fp8
    k_agg1<<<nblk, 256, 0, stream>>>((const unsigned short*)xq, off, csr, isd, agg1b, N);
    k_gemm12<<<gblk, 256, 0, stream>>>((const unsigned short*)agg1b, w1z, b1, w2z, isd, t2q, N);

    // layer 2: aggregate(fp8) + bias/relu/pool fused
    k_agg2p<<<nblk, 256, 0, stream>>>((const unsigned short*)t2q, off, csr, isd, b2,
                                      pooled, N);
    k_final<<<1, 128, 0, stream>>>(pooled, Wfc, bfc, out, 1.0f / (float)N);
}